// Round 1
// baseline (1064.687 us; speedup 1.0000x reference)
//
#include <hip/hip_runtime.h>

typedef short short8 __attribute__((ext_vector_type(8)));
typedef float f32x4 __attribute__((ext_vector_type(4)));

// ---------- constants ----------
#define BN_ 2048
#define DETER_ 8192
#define HID_ 1024
#define G_ 8

// workspace layout (bytes)
#define OFF_W1T  ((size_t)0)                       // [1024][8192] bf16
#define OFF_W2T  (OFF_W1T + 16777216)              // [1024][1024] bf16
#define OFF_WDT  (OFF_W2T + 2097152)               // [8][1024][4096] bf16
#define OFF_WOT  (OFF_WDT + 67108864)              // [8][3072][1024] bf16
#define OFF_DBF  (OFF_WOT + 50331648)              // deter bf16 [2048][8192]
#define OFF_SBF  (OFF_DBF + 33554432)              // stoch bf16 [2048][1024]
#define OFF_T1   (OFF_SBF + 4194304)               // t1 f32 [2048][1024]
#define OFF_T2   (OFF_T1 + 8388608)                // t2 f32 [2048][1024]
#define OFF_XC   (OFF_T2 + 8388608)                // xc bf16 [2048][3072]
#define OFF_HID  (OFF_XC + 12582912)               // hidden bf16 [2048][8192]
#define OFF_HN   (OFF_HID + 33554432)              // hnorm bf16 [2048][8192]
// total: 270,532,608 bytes

// ---------- helpers ----------
static __device__ __forceinline__ unsigned short f2bf(float x) {
  unsigned u = __float_as_uint(x);
  u += 0x7fffu + ((u >> 16) & 1u);
  return (unsigned short)(u >> 16);
}
static __device__ __forceinline__ float bf2f(unsigned short h) {
  return __uint_as_float(((unsigned)h) << 16);
}
static __device__ __forceinline__ float wave_sum(float v) {
#pragma unroll
  for (int off = 32; off > 0; off >>= 1) v += __shfl_xor(v, off, 64);
  return v;
}
static __device__ __forceinline__ float sigmoid_f(float x) { return 1.f / (1.f + __expf(-x)); }
static __device__ __forceinline__ float tanh_f(float x) {
  float e = __expf(2.f * x);
  return 1.f - 2.f / (e + 1.f);
}

typedef __attribute__((address_space(1))) unsigned int as1_u32;
typedef __attribute__((address_space(3))) unsigned int as3_u32;
static __device__ __forceinline__ void gl_lds16(const void* g, void* l) {
  __builtin_amdgcn_global_load_lds((as1_u32*)g, (as3_u32*)l, 16, 0, 0);
}

// ---------- cast kernels ----------
__global__ __launch_bounds__(256) void cast_v(const float4* __restrict__ src,
                                              ushort4* __restrict__ dst, int n4) {
  int i = blockIdx.x * 256 + threadIdx.x;
  if (i < n4) {
    float4 v = src[i];
    ushort4 o;
    o.x = f2bf(v.x); o.y = f2bf(v.y); o.z = f2bf(v.z); o.w = f2bf(v.w);
    dst[i] = o;
  }
}

// src [K][N] f32 -> dst [N][K] bf16 (transposed), blockIdx.z selects group
__global__ __launch_bounds__(256) void cast_transpose(const float* __restrict__ src,
                                                      unsigned short* __restrict__ dst,
                                                      int K, int N) {
  __shared__ float tile[32][33];
  src += (size_t)blockIdx.z * K * N;
  dst += (size_t)blockIdx.z * N * K;
  const int n0 = blockIdx.x * 32, k0 = blockIdx.y * 32;
  const int tx = threadIdx.x & 31, ty = threadIdx.x >> 5;  // ty 0..7
#pragma unroll
  for (int j = 0; j < 4; j++)
    tile[ty + j * 8][tx] = src[(size_t)(k0 + ty + j * 8) * N + n0 + tx];
  __syncthreads();
#pragma unroll
  for (int j = 0; j < 4; j++)
    dst[(size_t)(n0 + ty + j * 8) * K + k0 + tx] = f2bf(tile[tx][ty + j * 8]);
}

// ---------- GEMM: C = A(bf16)[M][K] * Bt(bf16)[N][K]^T + bias, f32 out ----------
__global__ __launch_bounds__(256) void gemm_bias(const unsigned short* __restrict__ A,
                                                 const unsigned short* __restrict__ Bt,
                                                 const float* __restrict__ bias,
                                                 float* __restrict__ C, int N, int K) {
  __shared__ unsigned short As[128 * 32];
  __shared__ unsigned short Bs[128 * 32];
  const int t = threadIdx.x;
  const int lane = t & 63, wid = t >> 6;
  const int wm = (wid & 1) * 64, wn = (wid >> 1) * 64;
  const int m0 = blockIdx.y * 128, n0 = blockIdx.x * 128;
  const int l15 = lane & 15, quad = lane >> 4;
  const int srow = t >> 2, scol = (t & 3) * 8;

  const unsigned short* Ag = A + (size_t)(m0 + srow) * K + scol;
  const unsigned short* Bg = Bt + (size_t)(n0 + srow) * K + scol;
  char* AsB = (char*)As;
  char* BsB = (char*)Bs;
  f32x4 acc[4][4] = {};

  for (int k0 = 0; k0 < K; k0 += 32) {
    gl_lds16(Ag + k0, AsB + t * 16);
    gl_lds16(Ag + (size_t)64 * K + k0, AsB + 4096 + t * 16);
    gl_lds16(Bg + k0, BsB + t * 16);
    gl_lds16(Bg + (size_t)64 * K + k0, BsB + 4096 + t * 16);
    __syncthreads();
    short8 af[4], bf[4];
#pragma unroll
    for (int mi = 0; mi < 4; mi++)
      af[mi] = *(const short8*)(As + (wm + mi * 16 + l15) * 32 + quad * 8);
#pragma unroll
    for (int ni = 0; ni < 4; ni++)
      bf[ni] = *(const short8*)(Bs + (wn + ni * 16 + l15) * 32 + quad * 8);
#pragma unroll
    for (int mi = 0; mi < 4; mi++)
#pragma unroll
      for (int ni = 0; ni < 4; ni++)
        acc[mi][ni] = __builtin_amdgcn_mfma_f32_16x16x32_bf16(af[mi], bf[ni], acc[mi][ni], 0, 0, 0);
    __syncthreads();
  }
#pragma unroll
  for (int mi = 0; mi < 4; mi++) {
    const int row = m0 + wm + mi * 16 + quad * 4;
#pragma unroll
    for (int ni = 0; ni < 4; ni++) {
      const int col = n0 + wn + ni * 16 + l15;
      const float bv = bias[col];
#pragma unroll
      for (int r = 0; r < 4; r++)
        C[(size_t)(row + r) * N + col] = acc[mi][ni][r] + bv;
    }
  }
}

// ---------- dyn block GEMM: A = [xc | deter_block_g], B = Wdynt[g], out hidden bf16 ----------
__global__ __launch_bounds__(256) void gemm_dyn(const unsigned short* __restrict__ xc,
                                                const unsigned short* __restrict__ dbf,
                                                const unsigned short* __restrict__ Wdt,
                                                unsigned short* __restrict__ hid) {
  __shared__ unsigned short As[128 * 32];
  __shared__ unsigned short Bs[128 * 32];
  const int t = threadIdx.x;
  const int lane = t & 63, wid = t >> 6;
  const int wm = (wid & 1) * 64, wn = (wid >> 1) * 64;
  const int g = blockIdx.z;
  const int m0 = blockIdx.y * 128, n0 = blockIdx.x * 128;
  const int l15 = lane & 15, quad = lane >> 4;
  const int srow = t >> 2, scol = (t & 3) * 8;

  const unsigned short* Ag1 = xc + (size_t)(m0 + srow) * 3072 + scol;
  const unsigned short* Ag2 = dbf + (size_t)(m0 + srow) * 8192 + g * 1024 + scol;
  const unsigned short* Bg = Wdt + (size_t)g * 1024 * 4096 + (size_t)(n0 + srow) * 4096 + scol;
  char* AsB = (char*)As;
  char* BsB = (char*)Bs;
  f32x4 acc[4][4] = {};

  for (int k0 = 0; k0 < 4096; k0 += 32) {
    if (k0 < 3072) {
      gl_lds16(Ag1 + k0, AsB + t * 16);
      gl_lds16(Ag1 + 64 * 3072 + k0, AsB + 4096 + t * 16);
    } else {
      gl_lds16(Ag2 + (k0 - 3072), AsB + t * 16);
      gl_lds16(Ag2 + 64 * 8192 + (k0 - 3072), AsB + 4096 + t * 16);
    }
    gl_lds16(Bg + k0, BsB + t * 16);
    gl_lds16(Bg + 64 * 4096 + k0, BsB + 4096 + t * 16);
    __syncthreads();
    short8 af[4], bf[4];
#pragma unroll
    for (int mi = 0; mi < 4; mi++)
      af[mi] = *(const short8*)(As + (wm + mi * 16 + l15) * 32 + quad * 8);
#pragma unroll
    for (int ni = 0; ni < 4; ni++)
      bf[ni] = *(const short8*)(Bs + (wn + ni * 16 + l15) * 32 + quad * 8);
#pragma unroll
    for (int mi = 0; mi < 4; mi++)
#pragma unroll
      for (int ni = 0; ni < 4; ni++)
        acc[mi][ni] = __builtin_amdgcn_mfma_f32_16x16x32_bf16(af[mi], bf[ni], acc[mi][ni], 0, 0, 0);
    __syncthreads();
  }
#pragma unroll
  for (int mi = 0; mi < 4; mi++) {
    const int row = m0 + wm + mi * 16 + quad * 4;
#pragma unroll
    for (int ni = 0; ni < 4; ni++) {
      const int col = g * 1024 + n0 + wn + ni * 16 + l15;
#pragma unroll
      for (int r = 0; r < 4; r++)
        hid[(size_t)(row + r) * 8192 + col] = f2bf(acc[mi][ni][r]);
    }
  }
}

// ---------- out block GEMM with fused gates (3 accumulator sets) ----------
__global__ __launch_bounds__(256) void gemm_out3(const unsigned short* __restrict__ hn,
                                                 const unsigned short* __restrict__ Wot,
                                                 const float* __restrict__ deter,
                                                 float* __restrict__ out) {
  __shared__ unsigned short As[128 * 32];       // 8 KB
  __shared__ unsigned short Bs[3 * 64 * 32];    // 12 KB
  const int t = threadIdx.x;
  const int lane = t & 63, wid = t >> 6;
  const int wm = (wid & 1) * 64, wn = (wid >> 1) * 32;
  const int g = blockIdx.z;
  const int m0 = blockIdx.y * 128, n0 = blockIdx.x * 64;
  const int l15 = lane & 15, quad = lane >> 4;
  const int srow = t >> 2, scol = (t & 3) * 8;

  const unsigned short* Ag = hn + (size_t)(m0 + srow) * 8192 + g * 1024 + scol;
  const unsigned short* Bg = Wot + (size_t)g * 3072 * 1024 + (size_t)(n0 + srow) * 1024 + scol;
  char* AsB = (char*)As;
  char* BsB = (char*)Bs;
  f32x4 aR[4][2] = {}, aM[4][2] = {}, aU[4][2] = {};

  for (int k0 = 0; k0 < 1024; k0 += 32) {
    gl_lds16(Ag + k0, AsB + t * 16);
    gl_lds16(Ag + 64 * 8192 + k0, AsB + 4096 + t * 16);
    gl_lds16(Bg + k0, BsB + t * 16);
    gl_lds16(Bg + 1024 * 1024 + k0, BsB + 4096 + t * 16);
    gl_lds16(Bg + 2 * 1024 * 1024 + k0, BsB + 8192 + t * 16);
    __syncthreads();
    short8 af[4], bR[2], bM[2], bU[2];
#pragma unroll
    for (int mi = 0; mi < 4; mi++)
      af[mi] = *(const short8*)(As + (wm + mi * 16 + l15) * 32 + quad * 8);
#pragma unroll
    for (int ni = 0; ni < 2; ni++) {
      bR[ni] = *(const short8*)(Bs + (wn + ni * 16 + l15) * 32 + quad * 8);
      bM[ni] = *(const short8*)(Bs + (64 + wn + ni * 16 + l15) * 32 + quad * 8);
      bU[ni] = *(const short8*)(Bs + (128 + wn + ni * 16 + l15) * 32 + quad * 8);
    }
#pragma unroll
    for (int mi = 0; mi < 4; mi++)
#pragma unroll
      for (int ni = 0; ni < 2; ni++) {
        aR[mi][ni] = __builtin_amdgcn_mfma_f32_16x16x32_bf16(af[mi], bR[ni], aR[mi][ni], 0, 0, 0);
        aM[mi][ni] = __builtin_amdgcn_mfma_f32_16x16x32_bf16(af[mi], bM[ni], aM[mi][ni], 0, 0, 0);
        aU[mi][ni] = __builtin_amdgcn_mfma_f32_16x16x32_bf16(af[mi], bU[ni], aU[mi][ni], 0, 0, 0);
      }
    __syncthreads();
  }
#pragma unroll
  for (int mi = 0; mi < 4; mi++) {
    const int row = m0 + wm + mi * 16 + quad * 4;
#pragma unroll
    for (int ni = 0; ni < 2; ni++) {
      const int col = g * 1024 + n0 + wn + ni * 16 + l15;
#pragma unroll
      for (int r = 0; r < 4; r++) {
        const size_t idx = (size_t)(row + r) * 8192 + col;
        const float rs = sigmoid_f(aR[mi][ni][r]);
        const float cd = tanh_f(rs * aM[mi][ni][r]);
        const float up = sigmoid_f(aU[mi][ni][r] - 1.f);
        out[idx] = up * cd + (1.f - up) * deter[idx];
      }
    }
  }
}

// ---------- rmsnorm + silu over 1024 cols -> xc segment ----------
__global__ __launch_bounds__(256) void norm_silu(const float* __restrict__ tin,
                                                 const float* __restrict__ gw,
                                                 unsigned short* __restrict__ xc, int xcoff) {
  const int r = blockIdx.x, t = threadIdx.x;
  const float4 v = *(const float4*)(tin + (size_t)r * 1024 + t * 4);
  float ss = v.x * v.x + v.y * v.y + v.z * v.z + v.w * v.w;
  ss = wave_sum(ss);
  __shared__ float red[4];
  if ((t & 63) == 0) red[t >> 6] = ss;
  __syncthreads();
  const float inv = rsqrtf((red[0] + red[1] + red[2] + red[3]) * (1.f / 1024.f) + 1e-6f);
  const float4 g4 = *(const float4*)(gw + t * 4);
  float a0 = v.x * inv * g4.x, a1 = v.y * inv * g4.y, a2 = v.z * inv * g4.z, a3 = v.w * inv * g4.w;
  ushort4 o;
  o.x = f2bf(a0 * sigmoid_f(a0));
  o.y = f2bf(a1 * sigmoid_f(a1));
  o.z = f2bf(a2 * sigmoid_f(a2));
  o.w = f2bf(a3 * sigmoid_f(a3));
  *(ushort4*)(xc + (size_t)r * 3072 + xcoff + t * 4) = o;
}

// ---------- action path: normalize, tiny GEMM (K=32), rmsnorm, silu ----------
__global__ __launch_bounds__(256) void act_mlp(const float* __restrict__ action,
                                               const float* __restrict__ W3,
                                               const float* __restrict__ b3,
                                               const float* __restrict__ g3,
                                               unsigned short* __restrict__ xc) {
  const int r = blockIdx.x, t = threadIdx.x;
  __shared__ float sA[32];
  if (t < 32) {
    float a = action[r * 32 + t];
    sA[t] = a / fmaxf(1.f, fabsf(a));
  }
  __syncthreads();
  float acc0 = 0.f, acc1 = 0.f, acc2 = 0.f, acc3 = 0.f;
#pragma unroll 8
  for (int k = 0; k < 32; k++) {
    const float a = sA[k];
    const float* wr = W3 + k * 1024 + t;
    acc0 += a * wr[0];
    acc1 += a * wr[256];
    acc2 += a * wr[512];
    acc3 += a * wr[768];
  }
  acc0 += b3[t]; acc1 += b3[t + 256]; acc2 += b3[t + 512]; acc3 += b3[t + 768];
  float ss = acc0 * acc0 + acc1 * acc1 + acc2 * acc2 + acc3 * acc3;
  ss = wave_sum(ss);
  __shared__ float red[4];
  if ((t & 63) == 0) red[t >> 6] = ss;
  __syncthreads();
  const float inv = rsqrtf((red[0] + red[1] + red[2] + red[3]) * (1.f / 1024.f) + 1e-6f);
  unsigned short* dst = xc + (size_t)r * 3072 + 2048;
  float a0 = acc0 * inv * g3[t], a1 = acc1 * inv * g3[t + 256];
  float a2 = acc2 * inv * g3[t + 512], a3 = acc3 * inv * g3[t + 768];
  dst[t] = f2bf(a0 * sigmoid_f(a0));
  dst[t + 256] = f2bf(a1 * sigmoid_f(a1));
  dst[t + 512] = f2bf(a2 * sigmoid_f(a2));
  dst[t + 768] = f2bf(a3 * sigmoid_f(a3));
}

// ---------- row rmsnorm over 8192 (hidden -> hnorm, bf16) ----------
__global__ __launch_bounds__(256) void hnorm_k(const unsigned short* __restrict__ hid,
                                               const float* __restrict__ gdyn,
                                               unsigned short* __restrict__ hn) {
  const int r = blockIdx.x, t = threadIdx.x;
  const uint4* rp = (const uint4*)(hid + (size_t)r * 8192);
  uint4 v[4];
  float ss = 0.f;
#pragma unroll
  for (int p = 0; p < 4; p++) {
    v[p] = rp[p * 256 + t];
    const unsigned a = v[p].x, b = v[p].y, c = v[p].z, d = v[p].w;
    float x0 = bf2f(a & 0xffff), x1 = bf2f(a >> 16);
    float x2 = bf2f(b & 0xffff), x3 = bf2f(b >> 16);
    float x4 = bf2f(c & 0xffff), x5 = bf2f(c >> 16);
    float x6 = bf2f(d & 0xffff), x7 = bf2f(d >> 16);
    ss += x0 * x0 + x1 * x1 + x2 * x2 + x3 * x3 + x4 * x4 + x5 * x5 + x6 * x6 + x7 * x7;
  }
  ss = wave_sum(ss);
  __shared__ float red[4];
  if ((t & 63) == 0) red[t >> 6] = ss;
  __syncthreads();
  const float inv = rsqrtf((red[0] + red[1] + red[2] + red[3]) * (1.f / 8192.f) + 1e-6f);
  uint4* op = (uint4*)(hn + (size_t)r * 8192);
#pragma unroll
  for (int p = 0; p < 4; p++) {
    const int c0 = (p * 256 + t) * 8;
    const float4 ga = *(const float4*)(gdyn + c0);
    const float4 gb = *(const float4*)(gdyn + c0 + 4);
    const unsigned a = v[p].x, b = v[p].y, c = v[p].z, d = v[p].w;
    unsigned o0 = f2bf(bf2f(a & 0xffff) * inv * ga.x);
    unsigned o1 = f2bf(bf2f(a >> 16) * inv * ga.y);
    unsigned o2 = f2bf(bf2f(b & 0xffff) * inv * ga.z);
    unsigned o3 = f2bf(bf2f(b >> 16) * inv * ga.w);
    unsigned o4 = f2bf(bf2f(c & 0xffff) * inv * gb.x);
    unsigned o5 = f2bf(bf2f(c >> 16) * inv * gb.y);
    unsigned o6 = f2bf(bf2f(d & 0xffff) * inv * gb.z);
    unsigned o7 = f2bf(bf2f(d >> 16) * inv * gb.w);
    uint4 w;
    w.x = o0 | (o1 << 16);
    w.y = o2 | (o3 << 16);
    w.z = o4 | (o5 << 16);
    w.w = o6 | (o7 << 16);
    op[p * 256 + t] = w;
  }
}

extern "C" void kernel_launch(void* const* d_in, const int* in_sizes, int n_in,
                              void* d_out, int out_size, void* d_ws, size_t ws_size,
                              hipStream_t stream) {
  (void)in_sizes; (void)n_in; (void)out_size; (void)ws_size;
  const float* deter  = (const float*)d_in[0];
  const float* stoch  = (const float*)d_in[1];
  const float* action = (const float*)d_in[2];
  const float* W1 = (const float*)d_in[3];
  const float* b1 = (const float*)d_in[4];
  const float* W2 = (const float*)d_in[5];
  const float* b2 = (const float*)d_in[6];
  const float* W3 = (const float*)d_in[7];
  const float* b3 = (const float*)d_in[8];
  const float* g1 = (const float*)d_in[9];
  const float* g2 = (const float*)d_in[10];
  const float* g3 = (const float*)d_in[11];
  const float* Wdyn = (const float*)d_in[12];
  const float* gdyn = (const float*)d_in[13];
  const float* Wout = (const float*)d_in[14];
  float* out = (float*)d_out;
  char* ws = (char*)d_ws;

  unsigned short* W1t = (unsigned short*)(ws + OFF_W1T);
  unsigned short* W2t = (unsigned short*)(ws + OFF_W2T);
  unsigned short* Wdt = (unsigned short*)(ws + OFF_WDT);
  unsigned short* Wot = (unsigned short*)(ws + OFF_WOT);
  unsigned short* dbf = (unsigned short*)(ws + OFF_DBF);
  unsigned short* sbf = (unsigned short*)(ws + OFF_SBF);
  float* t1 = (float*)(ws + OFF_T1);
  float* t2 = (float*)(ws + OFF_T2);
  unsigned short* xc = (unsigned short*)(ws + OFF_XC);
  unsigned short* hid = (unsigned short*)(ws + OFF_HID);
  unsigned short* hn = (unsigned short*)(ws + OFF_HN);

  const dim3 blk(256);

  // 1. casts
  cast_v<<<dim3(16384), blk, 0, stream>>>((const float4*)deter, (ushort4*)dbf, 2048 * 8192 / 4);
  cast_v<<<dim3(2048), blk, 0, stream>>>((const float4*)stoch, (ushort4*)sbf, 2048 * 1024 / 4);
  cast_transpose<<<dim3(32, 256, 1), blk, 0, stream>>>(W1, W1t, 8192, 1024);
  cast_transpose<<<dim3(32, 32, 1), blk, 0, stream>>>(W2, W2t, 1024, 1024);
  cast_transpose<<<dim3(32, 128, 8), blk, 0, stream>>>(Wdyn, Wdt, 4096, 1024);
  cast_transpose<<<dim3(96, 32, 8), blk, 0, stream>>>(Wout, Wot, 1024, 3072);

  // 2. the three input projections
  gemm_bias<<<dim3(8, 16), blk, 0, stream>>>(dbf, W1t, b1, t1, 1024, 8192);
  gemm_bias<<<dim3(8, 16), blk, 0, stream>>>(sbf, W2t, b2, t2, 1024, 1024);
  norm_silu<<<dim3(2048), blk, 0, stream>>>(t1, g1, xc, 0);
  norm_silu<<<dim3(2048), blk, 0, stream>>>(t2, g2, xc, 1024);
  act_mlp<<<dim3(2048), blk, 0, stream>>>(action, W3, b3, g3, xc);

  // 3. dyn block-diagonal GEMM -> hidden (bf16)
  gemm_dyn<<<dim3(8, 16, 8), blk, 0, stream>>>(xc, dbf, Wdt, hid);

  // 4. full-row rmsnorm -> hnorm (bf16)
  hnorm_k<<<dim3(2048), blk, 0, stream>>>(hid, gdyn, hn);

  // 5. out block GEMM + fused gates -> next_deter (f32)
  gemm_out3<<<dim3(16, 16, 8), blk, 0, stream>>>(hn, Wot, deter, out);
}

// Round 2
// 842.247 us; speedup vs baseline: 1.2641x; 1.2641x over previous
//
#include <hip/hip_runtime.h>

typedef short short8 __attribute__((ext_vector_type(8)));
typedef float f32x4 __attribute__((ext_vector_type(4)));

// workspace layout (bytes)
#define OFF_W1T  ((size_t)0)                       // [1024][8192] bf16
#define OFF_W2T  (OFF_W1T + 16777216)              // [1024][1024] bf16
#define OFF_WDT  (OFF_W2T + 2097152)               // [8][1024][4096] bf16
#define OFF_WOT  (OFF_WDT + 67108864)              // [8][3072][1024] bf16
#define OFF_DBF  (OFF_WOT + 50331648)              // deter bf16 [2048][8192]
#define OFF_SBF  (OFF_DBF + 33554432)              // stoch bf16 [2048][1024]
#define OFF_T2   (OFF_SBF + 4194304)               // t2 f32 [2048][1024]
#define OFF_XC   (OFF_T2 + 8388608)                // xc bf16 [2048][3072]
#define OFF_HID  (OFF_XC + 12582912)               // hidden bf16 [2048][8192]; ALSO splitk partials f32 [8][2048][1024] (64MB = HID+HN)
#define OFF_HN   (OFF_HID + 33554432)              // hnorm bf16 [2048][8192]

// ---------- helpers ----------
static __device__ __forceinline__ unsigned short f2bf(float x) {
  unsigned u = __float_as_uint(x);
  u += 0x7fffu + ((u >> 16) & 1u);
  return (unsigned short)(u >> 16);
}
static __device__ __forceinline__ float bf2f(unsigned short h) {
  return __uint_as_float(((unsigned)h) << 16);
}
static __device__ __forceinline__ float wave_sum(float v) {
#pragma unroll
  for (int off = 32; off > 0; off >>= 1) v += __shfl_xor(v, off, 64);
  return v;
}
static __device__ __forceinline__ float sigmoid_f(float x) { return 1.f / (1.f + __expf(-x)); }
static __device__ __forceinline__ float tanh_f(float x) {
  float e = __expf(2.f * x);
  return 1.f - 2.f / (e + 1.f);
}

typedef __attribute__((address_space(1))) unsigned int as1_u32;
typedef __attribute__((address_space(3))) unsigned int as3_u32;
static __device__ __forceinline__ void gl_lds16(const void* g, void* l) {
  __builtin_amdgcn_global_load_lds((as1_u32*)g, (as3_u32*)l, 16, 0, 0);
}

// ---------- cast kernels ----------
__global__ __launch_bounds__(256) void cast_v(const float4* __restrict__ src,
                                              ushort4* __restrict__ dst, int n4) {
  int i = blockIdx.x * 256 + threadIdx.x;
  if (i < n4) {
    float4 v = src[i];
    ushort4 o;
    o.x = f2bf(v.x); o.y = f2bf(v.y); o.z = f2bf(v.z); o.w = f2bf(v.w);
    dst[i] = o;
  }
}

// src [K][N] f32 -> dst [N][K] bf16 (transposed), blockIdx.z selects group
__global__ __launch_bounds__(256) void cast_transpose(const float* __restrict__ src,
                                                      unsigned short* __restrict__ dst,
                                                      int K, int N) {
  __shared__ float tile[32][33];
  src += (size_t)blockIdx.z * K * N;
  dst += (size_t)blockIdx.z * N * K;
  const int n0 = blockIdx.x * 32, k0 = blockIdx.y * 32;
  const int tx = threadIdx.x & 31, ty = threadIdx.x >> 5;  // ty 0..7
#pragma unroll
  for (int j = 0; j < 4; j++)
    tile[ty + j * 8][tx] = src[(size_t)(k0 + ty + j * 8) * N + n0 + tx];
  __syncthreads();
#pragma unroll
  for (int j = 0; j < 4; j++)
    dst[(size_t)(n0 + ty + j * 8) * K + k0 + tx] = f2bf(tile[tx][ty + j * 8]);
}

// ---------- generic 128x128 GEMM + bias (f32 out). Used for W2 (small K). ----------
__global__ __launch_bounds__(256, 4) void gemm_bias(const unsigned short* __restrict__ A,
                                                    const unsigned short* __restrict__ Bt,
                                                    const float* __restrict__ bias,
                                                    float* __restrict__ C, int N, int K) {
  __shared__ unsigned short As[128 * 32];
  __shared__ unsigned short Bs[128 * 32];
  const int t = threadIdx.x;
  const int lane = t & 63, wid = t >> 6;
  const int wm = (wid & 1) * 64, wn = (wid >> 1) * 64;
  const int m0 = blockIdx.y * 128, n0 = blockIdx.x * 128;
  const int l15 = lane & 15, quad = lane >> 4;
  const int srow = t >> 2, scol = (t & 3) * 8;

  const unsigned short* Ag = A + (size_t)(m0 + srow) * K + scol;
  const unsigned short* Bg = Bt + (size_t)(n0 + srow) * K + scol;
  char* AsB = (char*)As;
  char* BsB = (char*)Bs;
  f32x4 acc[4][4] = {};

  for (int k0 = 0; k0 < K; k0 += 32) {
    gl_lds16(Ag + k0, AsB + t * 16);
    gl_lds16(Ag + (size_t)64 * K + k0, AsB + 4096 + t * 16);
    gl_lds16(Bg + k0, BsB + t * 16);
    gl_lds16(Bg + (size_t)64 * K + k0, BsB + 4096 + t * 16);
    __syncthreads();
    short8 af[4], bf[4];
#pragma unroll
    for (int mi = 0; mi < 4; mi++)
      af[mi] = *(const short8*)(As + (wm + mi * 16 + l15) * 32 + quad * 8);
#pragma unroll
    for (int ni = 0; ni < 4; ni++)
      bf[ni] = *(const short8*)(Bs + (wn + ni * 16 + l15) * 32 + quad * 8);
#pragma unroll
    for (int mi = 0; mi < 4; mi++)
#pragma unroll
      for (int ni = 0; ni < 4; ni++)
        acc[mi][ni] = __builtin_amdgcn_mfma_f32_16x16x32_bf16(af[mi], bf[ni], acc[mi][ni], 0, 0, 0);
    __syncthreads();
  }
#pragma unroll
  for (int mi = 0; mi < 4; mi++) {
    const int row = m0 + wm + mi * 16 + quad * 4;
#pragma unroll
    for (int ni = 0; ni < 4; ni++) {
      const int col = n0 + wn + ni * 16 + l15;
      const float bv = bias[col];
#pragma unroll
      for (int r = 0; r < 4; r++)
        C[(size_t)(row + r) * N + col] = acc[mi][ni][r] + bv;
    }
  }
}

// ---------- split-K GEMM for W1: K=8192 in 8 chunks of 1024, f32 partials ----------
__global__ __launch_bounds__(256, 4) void gemm_splitk(const unsigned short* __restrict__ A,
                                                      const unsigned short* __restrict__ Bt,
                                                      float* __restrict__ P) {
  __shared__ unsigned short As[128 * 32];
  __shared__ unsigned short Bs[128 * 32];
  const int t = threadIdx.x;
  const int lane = t & 63, wid = t >> 6;
  const int wm = (wid & 1) * 64, wn = (wid >> 1) * 64;
  const int m0 = blockIdx.y * 128, n0 = blockIdx.x * 128;
  const int kbase = blockIdx.z * 1024;
  const int l15 = lane & 15, quad = lane >> 4;
  const int srow = t >> 2, scol = (t & 3) * 8;

  const unsigned short* Ag = A + (size_t)(m0 + srow) * 8192 + kbase + scol;
  const unsigned short* Bg = Bt + (size_t)(n0 + srow) * 8192 + kbase + scol;
  char* AsB = (char*)As;
  char* BsB = (char*)Bs;
  f32x4 acc[4][4] = {};

  for (int k0 = 0; k0 < 1024; k0 += 32) {
    gl_lds16(Ag + k0, AsB + t * 16);
    gl_lds16(Ag + (size_t)64 * 8192 + k0, AsB + 4096 + t * 16);
    gl_lds16(Bg + k0, BsB + t * 16);
    gl_lds16(Bg + (size_t)64 * 8192 + k0, BsB + 4096 + t * 16);
    __syncthreads();
    short8 af[4], bf[4];
#pragma unroll
    for (int mi = 0; mi < 4; mi++)
      af[mi] = *(const short8*)(As + (wm + mi * 16 + l15) * 32 + quad * 8);
#pragma unroll
    for (int ni = 0; ni < 4; ni++)
      bf[ni] = *(const short8*)(Bs + (wn + ni * 16 + l15) * 32 + quad * 8);
#pragma unroll
    for (int mi = 0; mi < 4; mi++)
#pragma unroll
      for (int ni = 0; ni < 4; ni++)
        acc[mi][ni] = __builtin_amdgcn_mfma_f32_16x16x32_bf16(af[mi], bf[ni], acc[mi][ni], 0, 0, 0);
    __syncthreads();
  }
  float* Pb = P + (size_t)blockIdx.z * 2048 * 1024;
#pragma unroll
  for (int mi = 0; mi < 4; mi++) {
    const int row = m0 + wm + mi * 16 + quad * 4;
#pragma unroll
    for (int ni = 0; ni < 4; ni++) {
      const int col = n0 + wn + ni * 16 + l15;
#pragma unroll
      for (int r = 0; r < 4; r++)
        Pb[(size_t)(row + r) * 1024 + col] = acc[mi][ni][r];
    }
  }
}

// ---------- reduce 8 split-K partials + bias, rmsnorm, silu -> xc[:,0:1024] ----------
__global__ __launch_bounds__(256) void reduce_norm_silu(const float* __restrict__ P,
                                                        const float* __restrict__ b1,
                                                        const float* __restrict__ g1,
                                                        unsigned short* __restrict__ xc) {
  const int r = blockIdx.x, t = threadIdx.x;
  const float4* base = (const float4*)(P + (size_t)r * 1024) + t;
  float4 v = *base;
#pragma unroll
  for (int s = 1; s < 8; s++) {
    const float4 p = base[(size_t)s * 2048 * 256];
    v.x += p.x; v.y += p.y; v.z += p.z; v.w += p.w;
  }
  const float4 b4 = *((const float4*)b1 + t);
  v.x += b4.x; v.y += b4.y; v.z += b4.z; v.w += b4.w;
  float ss = v.x * v.x + v.y * v.y + v.z * v.z + v.w * v.w;
  ss = wave_sum(ss);
  __shared__ float red[4];
  if ((t & 63) == 0) red[t >> 6] = ss;
  __syncthreads();
  const float inv = rsqrtf((red[0] + red[1] + red[2] + red[3]) * (1.f / 1024.f) + 1e-6f);
  const float4 g4 = *((const float4*)g1 + t);
  float a0 = v.x * inv * g4.x, a1 = v.y * inv * g4.y, a2 = v.z * inv * g4.z, a3 = v.w * inv * g4.w;
  ushort4 o;
  o.x = f2bf(a0 * sigmoid_f(a0));
  o.y = f2bf(a1 * sigmoid_f(a1));
  o.z = f2bf(a2 * sigmoid_f(a2));
  o.w = f2bf(a3 * sigmoid_f(a3));
  *(ushort4*)(xc + (size_t)r * 3072 + t * 4) = o;
}

// ---------- dyn block GEMM: A = [xc | deter_block_g], B = Wdynt[g], out hidden bf16 ----------
__global__ __launch_bounds__(256, 4) void gemm_dyn(const unsigned short* __restrict__ xc,
                                                   const unsigned short* __restrict__ dbf,
                                                   const unsigned short* __restrict__ Wdt,
                                                   unsigned short* __restrict__ hid) {
  __shared__ unsigned short As[128 * 32];
  __shared__ unsigned short Bs[128 * 32];
  const int t = threadIdx.x;
  const int lane = t & 63, wid = t >> 6;
  const int wm = (wid & 1) * 64, wn = (wid >> 1) * 64;
  const int g = blockIdx.z;
  const int m0 = blockIdx.y * 128, n0 = blockIdx.x * 128;
  const int l15 = lane & 15, quad = lane >> 4;
  const int srow = t >> 2, scol = (t & 3) * 8;

  const unsigned short* Ag1 = xc + (size_t)(m0 + srow) * 3072 + scol;
  const unsigned short* Ag2 = dbf + (size_t)(m0 + srow) * 8192 + g * 1024 + scol - 3072;
  const unsigned short* Bg = Wdt + (size_t)g * 1024 * 4096 + (size_t)(n0 + srow) * 4096 + scol;
  char* AsB = (char*)As;
  char* BsB = (char*)Bs;
  const unsigned short* pa0 = As + (wm + l15) * 32 + quad * 8;
  const unsigned short* pb0 = Bs + (wn + l15) * 32 + quad * 8;
  f32x4 acc[4][4] = {};

  for (int k0 = 0; k0 < 4096; k0 += 32) {
    if (k0 < 3072) {
      gl_lds16(Ag1 + k0, AsB + t * 16);
      gl_lds16(Ag1 + 64 * 3072 + k0, AsB + 4096 + t * 16);
    } else {
      gl_lds16(Ag2 + k0, AsB + t * 16);
      gl_lds16(Ag2 + 64 * 8192 + k0, AsB + 4096 + t * 16);
    }
    gl_lds16(Bg + k0, BsB + t * 16);
    gl_lds16(Bg + 64 * 4096 + k0, BsB + 4096 + t * 16);
    __syncthreads();
    short8 af[4], bf[4];
#pragma unroll
    for (int mi = 0; mi < 4; mi++)
      af[mi] = *(const short8*)(pa0 + mi * 16 * 32);
#pragma unroll
    for (int ni = 0; ni < 4; ni++)
      bf[ni] = *(const short8*)(pb0 + ni * 16 * 32);
#pragma unroll
    for (int mi = 0; mi < 4; mi++)
#pragma unroll
      for (int ni = 0; ni < 4; ni++)
        acc[mi][ni] = __builtin_amdgcn_mfma_f32_16x16x32_bf16(af[mi], bf[ni], acc[mi][ni], 0, 0, 0);
    __syncthreads();
  }
#pragma unroll
  for (int mi = 0; mi < 4; mi++) {
    const int row = m0 + wm + mi * 16 + quad * 4;
#pragma unroll
    for (int ni = 0; ni < 4; ni++) {
      const int col = g * 1024 + n0 + wn + ni * 16 + l15;
#pragma unroll
      for (int r = 0; r < 4; r++)
        hid[(size_t)(row + r) * 8192 + col] = f2bf(acc[mi][ni][r]);
    }
  }
}

// ---------- out block GEMM with fused gates (3 accumulator sets) ----------
__global__ __launch_bounds__(256, 3) void gemm_out3(const unsigned short* __restrict__ hn,
                                                    const unsigned short* __restrict__ Wot,
                                                    const float* __restrict__ deter,
                                                    float* __restrict__ out) {
  __shared__ unsigned short As[128 * 32];       // 8 KB
  __shared__ unsigned short Bs[3 * 64 * 32];    // 12 KB
  const int t = threadIdx.x;
  const int lane = t & 63, wid = t >> 6;
  const int wm = (wid & 1) * 64, wn = (wid >> 1) * 32;
  const int g = blockIdx.z;
  const int m0 = blockIdx.y * 128, n0 = blockIdx.x * 64;
  const int l15 = lane & 15, quad = lane >> 4;
  const int srow = t >> 2, scol = (t & 3) * 8;

  const unsigned short* Ag = hn + (size_t)(m0 + srow) * 8192 + g * 1024 + scol;
  const unsigned short* Bg = Wot + (size_t)g * 3072 * 1024 + (size_t)(n0 + srow) * 1024 + scol;
  char* AsB = (char*)As;
  char* BsB = (char*)Bs;
  f32x4 aR[4][2] = {}, aM[4][2] = {}, aU[4][2] = {};

  for (int k0 = 0; k0 < 1024; k0 += 32) {
    gl_lds16(Ag + k0, AsB + t * 16);
    gl_lds16(Ag + 64 * 8192 + k0, AsB + 4096 + t * 16);
    gl_lds16(Bg + k0, BsB + t * 16);
    gl_lds16(Bg + 1024 * 1024 + k0, BsB + 4096 + t * 16);
    gl_lds16(Bg + 2 * 1024 * 1024 + k0, BsB + 8192 + t * 16);
    __syncthreads();
    short8 af[4], bR[2], bM[2], bU[2];
#pragma unroll
    for (int mi = 0; mi < 4; mi++)
      af[mi] = *(const short8*)(As + (wm + mi * 16 + l15) * 32 + quad * 8);
#pragma unroll
    for (int ni = 0; ni < 2; ni++) {
      bR[ni] = *(const short8*)(Bs + (wn + ni * 16 + l15) * 32 + quad * 8);
      bM[ni] = *(const short8*)(Bs + (64 + wn + ni * 16 + l15) * 32 + quad * 8);
      bU[ni] = *(const short8*)(Bs + (128 + wn + ni * 16 + l15) * 32 + quad * 8);
    }
#pragma unroll
    for (int mi = 0; mi < 4; mi++)
#pragma unroll
      for (int ni = 0; ni < 2; ni++) {
        aR[mi][ni] = __builtin_amdgcn_mfma_f32_16x16x32_bf16(af[mi], bR[ni], aR[mi][ni], 0, 0, 0);
        aM[mi][ni] = __builtin_amdgcn_mfma_f32_16x16x32_bf16(af[mi], bM[ni], aM[mi][ni], 0, 0, 0);
        aU[mi][ni] = __builtin_amdgcn_mfma_f32_16x16x32_bf16(af[mi], bU[ni], aU[mi][ni], 0, 0, 0);
      }
    __syncthreads();
  }
#pragma unroll
  for (int mi = 0; mi < 4; mi++) {
    const int row = m0 + wm + mi * 16 + quad * 4;
#pragma unroll
    for (int ni = 0; ni < 2; ni++) {
      const int col = g * 1024 + n0 + wn + ni * 16 + l15;
#pragma unroll
      for (int r = 0; r < 4; r++) {
        const size_t idx = (size_t)(row + r) * 8192 + col;
        const float rs = sigmoid_f(aR[mi][ni][r]);
        const float cd = tanh_f(rs * aM[mi][ni][r]);
        const float up = sigmoid_f(aU[mi][ni][r] - 1.f);
        out[idx] = up * cd + (1.f - up) * deter[idx];
      }
    }
  }
}

// ---------- rmsnorm + silu over 1024 cols -> xc segment (W2 path) ----------
__global__ __launch_bounds__(256) void norm_silu(const float* __restrict__ tin,
                                                 const float* __restrict__ gw,
                                                 unsigned short* __restrict__ xc, int xcoff) {
  const int r = blockIdx.x, t = threadIdx.x;
  const float4 v = *(const float4*)(tin + (size_t)r * 1024 + t * 4);
  float ss = v.x * v.x + v.y * v.y + v.z * v.z + v.w * v.w;
  ss = wave_sum(ss);
  __shared__ float red[4];
  if ((t & 63) == 0) red[t >> 6] = ss;
  __syncthreads();
  const float inv = rsqrtf((red[0] + red[1] + red[2] + red[3]) * (1.f / 1024.f) + 1e-6f);
  const float4 g4 = *(const float4*)(gw + t * 4);
  float a0 = v.x * inv * g4.x, a1 = v.y * inv * g4.y, a2 = v.z * inv * g4.z, a3 = v.w * inv * g4.w;
  ushort4 o;
  o.x = f2bf(a0 * sigmoid_f(a0));
  o.y = f2bf(a1 * sigmoid_f(a1));
  o.z = f2bf(a2 * sigmoid_f(a2));
  o.w = f2bf(a3 * sigmoid_f(a3));
  *(ushort4*)(xc + (size_t)r * 3072 + xcoff + t * 4) = o;
}

// ---------- action path: normalize, tiny GEMM (K=32), rmsnorm, silu ----------
__global__ __launch_bounds__(256) void act_mlp(const float* __restrict__ action,
                                               const float* __restrict__ W3,
                                               const float* __restrict__ b3,
                                               const float* __restrict__ g3,
                                               unsigned short* __restrict__ xc) {
  const int r = blockIdx.x, t = threadIdx.x;
  __shared__ float sA[32];
  if (t < 32) {
    float a = action[r * 32 + t];
    sA[t] = a / fmaxf(1.f, fabsf(a));
  }
  __syncthreads();
  float acc0 = 0.f, acc1 = 0.f, acc2 = 0.f, acc3 = 0.f;
#pragma unroll 8
  for (int k = 0; k < 32; k++) {
    const float a = sA[k];
    const float* wr = W3 + k * 1024 + t;
    acc0 += a * wr[0];
    acc1 += a * wr[256];
    acc2 += a * wr[512];
    acc3 += a * wr[768];
  }
  acc0 += b3[t]; acc1 += b3[t + 256]; acc2 += b3[t + 512]; acc3 += b3[t + 768];
  float ss = acc0 * acc0 + acc1 * acc1 + acc2 * acc2 + acc3 * acc3;
  ss = wave_sum(ss);
  __shared__ float red[4];
  if ((t & 63) == 0) red[t >> 6] = ss;
  __syncthreads();
  const float inv = rsqrtf((red[0] + red[1] + red[2] + red[3]) * (1.f / 1024.f) + 1e-6f);
  unsigned short* dst = xc + (size_t)r * 3072 + 2048;
  float a0 = acc0 * inv * g3[t], a1 = acc1 * inv * g3[t + 256];
  float a2 = acc2 * inv * g3[t + 512], a3 = acc3 * inv * g3[t + 768];
  dst[t] = f2bf(a0 * sigmoid_f(a0));
  dst[t + 256] = f2bf(a1 * sigmoid_f(a1));
  dst[t + 512] = f2bf(a2 * sigmoid_f(a2));
  dst[t + 768] = f2bf(a3 * sigmoid_f(a3));
}

// ---------- row rmsnorm over 8192 (hidden -> hnorm, bf16) ----------
__global__ __launch_bounds__(256) void hnorm_k(const unsigned short* __restrict__ hid,
                                               const float* __restrict__ gdyn,
                                               unsigned short* __restrict__ hn) {
  const int r = blockIdx.x, t = threadIdx.x;
  const uint4* rp = (const uint4*)(hid + (size_t)r * 8192);
  uint4 v[4];
  float ss = 0.f;
#pragma unroll
  for (int p = 0; p < 4; p++) {
    v[p] = rp[p * 256 + t];
    const unsigned a = v[p].x, b = v[p].y, c = v[p].z, d = v[p].w;
    float x0 = bf2f(a & 0xffff), x1 = bf2f(a >> 16);
    float x2 = bf2f(b & 0xffff), x3 = bf2f(b >> 16);
    float x4 = bf2f(c & 0xffff), x5 = bf2f(c >> 16);
    float x6 = bf2f(d & 0xffff), x7 = bf2f(d >> 16);
    ss += x0 * x0 + x1 * x1 + x2 * x2 + x3 * x3 + x4 * x4 + x5 * x5 + x6 * x6 + x7 * x7;
  }
  ss = wave_sum(ss);
  __shared__ float red[4];
  if ((t & 63) == 0) red[t >> 6] = ss;
  __syncthreads();
  const float inv = rsqrtf((red[0] + red[1] + red[2] + red[3]) * (1.f / 8192.f) + 1e-6f);
  uint4* op = (uint4*)(hn + (size_t)r * 8192);
#pragma unroll
  for (int p = 0; p < 4; p++) {
    const int c0 = (p * 256 + t) * 8;
    const float4 ga = *(const float4*)(gdyn + c0);
    const float4 gb = *(const float4*)(gdyn + c0 + 4);
    const unsigned a = v[p].x, b = v[p].y, c = v[p].z, d = v[p].w;
    unsigned o0 = f2bf(bf2f(a & 0xffff) * inv * ga.x);
    unsigned o1 = f2bf(bf2f(a >> 16) * inv * ga.y);
    unsigned o2 = f2bf(bf2f(b & 0xffff) * inv * ga.z);
    unsigned o3 = f2bf(bf2f(b >> 16) * inv * ga.w);
    unsigned o4 = f2bf(bf2f(c & 0xffff) * inv * gb.x);
    unsigned o5 = f2bf(bf2f(c >> 16) * inv * gb.y);
    unsigned o6 = f2bf(bf2f(d & 0xffff) * inv * gb.z);
    unsigned o7 = f2bf(bf2f(d >> 16) * inv * gb.w);
    uint4 w;
    w.x = o0 | (o1 << 16);
    w.y = o2 | (o3 << 16);
    w.z = o4 | (o5 << 16);
    w.w = o6 | (o7 << 16);
    op[p * 256 + t] = w;
  }
}

extern "C" void kernel_launch(void* const* d_in, const int* in_sizes, int n_in,
                              void* d_out, int out_size, void* d_ws, size_t ws_size,
                              hipStream_t stream) {
  (void)in_sizes; (void)n_in; (void)out_size; (void)ws_size;
  const float* deter  = (const float*)d_in[0];
  const float* stoch  = (const float*)d_in[1];
  const float* action = (const float*)d_in[2];
  const float* W1 = (const float*)d_in[3];
  const float* b1 = (const float*)d_in[4];
  const float* W2 = (const float*)d_in[5];
  const float* b2 = (const float*)d_in[6];
  const float* W3 = (const float*)d_in[7];
  const float* b3 = (const float*)d_in[8];
  const float* g1 = (const float*)d_in[9];
  const float* g2 = (const float*)d_in[10];
  const float* g3 = (const float*)d_in[11];
  const float* Wdyn = (const float*)d_in[12];
  const float* gdyn = (const float*)d_in[13];
  const float* Wout = (const float*)d_in[14];
  float* out = (float*)d_out;
  char* ws = (char*)d_ws;

  unsigned short* W1t = (unsigned short*)(ws + OFF_W1T);
  unsigned short* W2t = (unsigned short*)(ws + OFF_W2T);
  unsigned short* Wdt = (unsigned short*)(ws + OFF_WDT);
  unsigned short* Wot = (unsigned short*)(ws + OFF_WOT);
  unsigned short* dbf = (unsigned short*)(ws + OFF_DBF);
  unsigned short* sbf = (unsigned short*)(ws + OFF_SBF);
  float* t2 = (float*)(ws + OFF_T2);
  unsigned short* xc = (unsigned short*)(ws + OFF_XC);
  unsigned short* hid = (unsigned short*)(ws + OFF_HID);
  unsigned short* hn = (unsigned short*)(ws + OFF_HN);
  float* Pk = (float*)(ws + OFF_HID);  // split-K partials, reused before hid is live

  const dim3 blk(256);

  // 1. casts
  cast_v<<<dim3(16384), blk, 0, stream>>>((const float4*)deter, (ushort4*)dbf, 2048 * 8192 / 4);
  cast_v<<<dim3(2048), blk, 0, stream>>>((const float4*)stoch, (ushort4*)sbf, 2048 * 1024 / 4);
  cast_transpose<<<dim3(32, 256, 1), blk, 0, stream>>>(W1, W1t, 8192, 1024);
  cast_transpose<<<dim3(32, 32, 1), blk, 0, stream>>>(W2, W2t, 1024, 1024);
  cast_transpose<<<dim3(32, 128, 8), blk, 0, stream>>>(Wdyn, Wdt, 4096, 1024);
  cast_transpose<<<dim3(96, 32, 8), blk, 0, stream>>>(Wout, Wot, 1024, 3072);

  // 2. input projections: W1 via split-K(8) + fused reduce/norm/silu; W2 direct
  gemm_splitk<<<dim3(8, 16, 8), blk, 0, stream>>>(dbf, W1t, Pk);
  gemm_bias<<<dim3(8, 16), blk, 0, stream>>>(sbf, W2t, b2, t2, 1024, 1024);
  reduce_norm_silu<<<dim3(2048), blk, 0, stream>>>(Pk, b1, g1, xc);
  norm_silu<<<dim3(2048), blk, 0, stream>>>(t2, g2, xc, 1024);
  act_mlp<<<dim3(2048), blk, 0, stream>>>(action, W3, b3, g3, xc);

  // 3. dyn block-diagonal GEMM -> hidden (bf16); overwrites Pk region (xc already built)
  gemm_dyn<<<dim3(8, 16, 8), blk, 0, stream>>>(xc, dbf, Wdt, hid);

  // 4. full-row rmsnorm -> hnorm (bf16)
  hnorm_k<<<dim3(2048), blk, 0, stream>>>(hid, gdyn, hn);

  // 5. out block GEMM + fused gates -> next_deter (f32)
  gemm_out3<<<dim3(16, 16, 8), blk, 0, stream>>>(hn, Wot, deter, out);
}

// Round 3
// 829.772 us; speedup vs baseline: 1.2831x; 1.0150x over previous
//
#include <hip/hip_runtime.h>

typedef short short8 __attribute__((ext_vector_type(8)));
typedef float f32x4 __attribute__((ext_vector_type(4)));

// workspace layout (bytes)
#define OFF_W1T  ((size_t)0)                       // [1024][8192] bf16
#define OFF_W2T  (OFF_W1T + 16777216)              // [1024][1024] bf16
#define OFF_WDT  (OFF_W2T + 2097152)               // [8][1024][4096] bf16
#define OFF_WOT  (OFF_WDT + 67108864)              // [8][3072][1024] bf16
#define OFF_DBF  (OFF_WOT + 50331648)              // deter bf16 [2048][8192]
#define OFF_SBF  (OFF_DBF + 33554432)              // stoch bf16 [2048][1024]
#define OFF_T2   (OFF_SBF + 4194304)               // t2 f32 [2048][1024]
#define OFF_XC   (OFF_T2 + 8388608)                // xc bf16 [2048][3072]
#define OFF_HID  (OFF_XC + 12582912)               // hidden bf16 [2048][8192]; ALSO splitk partials f32 [8][2048][1024]
#define OFF_HN   (OFF_HID + 33554432)              // hnorm bf16 [2048][8192]

// ---------- helpers ----------
static __device__ __forceinline__ unsigned short f2bf(float x) {
  unsigned u = __float_as_uint(x);
  u += 0x7fffu + ((u >> 16) & 1u);
  return (unsigned short)(u >> 16);
}
static __device__ __forceinline__ float bf2f(unsigned short h) {
  return __uint_as_float(((unsigned)h) << 16);
}
static __device__ __forceinline__ float wave_sum(float v) {
#pragma unroll
  for (int off = 32; off > 0; off >>= 1) v += __shfl_xor(v, off, 64);
  return v;
}
static __device__ __forceinline__ float sigmoid_f(float x) { return 1.f / (1.f + __expf(-x)); }
static __device__ __forceinline__ float tanh_f(float x) {
  float e = __expf(2.f * x);
  return 1.f - 2.f / (e + 1.f);
}

typedef __attribute__((address_space(1))) unsigned int as1_u32;
typedef __attribute__((address_space(3))) unsigned int as3_u32;
static __device__ __forceinline__ void gl_lds16(const void* g, void* l) {
  __builtin_amdgcn_global_load_lds((as1_u32*)g, (as3_u32*)l, 16, 0, 0);
}

// ---------- cast kernels ----------
__global__ __launch_bounds__(256) void cast_v(const float4* __restrict__ src,
                                              ushort4* __restrict__ dst, int n4) {
  int i = blockIdx.x * 256 + threadIdx.x;
  if (i < n4) {
    float4 v = src[i];
    ushort4 o;
    o.x = f2bf(v.x); o.y = f2bf(v.y); o.z = f2bf(v.z); o.w = f2bf(v.w);
    dst[i] = o;
  }
}

// src [K][N] f32 -> dst [N][K] bf16 (transposed), 64x64 tiles, 16B/lane stores.
// blockIdx.z selects group.
// LDS row stride 65 words: write-phase column reads land 2-way (free, m136).
__global__ __launch_bounds__(256) void cast_transpose(const float* __restrict__ src,
                                                      unsigned short* __restrict__ dst,
                                                      int K, int N) {
  __shared__ float tile[64 * 65];
  src += (size_t)blockIdx.z * K * N;
  dst += (size_t)blockIdx.z * N * K;
  const int n0 = blockIdx.x * 64, k0 = blockIdx.y * 64;
  const int t = threadIdx.x;
  // read phase: [64k][64n], float4 coalesced along n
  {
    const int kr = t >> 4;            // 0..15
    const int nc = (t & 15) * 4;      // 0..60
#pragma unroll
    for (int j = 0; j < 4; j++) {
      const int k = kr + j * 16;
      const float4 v = *(const float4*)(src + (size_t)(k0 + k) * N + n0 + nc);
      float* tp = tile + k * 65 + nc;
      tp[0] = v.x; tp[1] = v.y; tp[2] = v.z; tp[3] = v.w;
    }
  }
  __syncthreads();
  // write phase: each thread emits dst[n0+n][k0+kq .. kq+15] as 2x 16B stores
  {
    const int n = t >> 2;             // 0..63
    const int kq = (t & 3) * 16;      // 0..48
    ushort4 o[4];
#pragma unroll
    for (int q = 0; q < 4; q++) {
      const float* tp = tile + (kq + q * 4) * 65 + n;
      o[q].x = f2bf(tp[0 * 65]);
      o[q].y = f2bf(tp[1 * 65]);
      o[q].z = f2bf(tp[2 * 65]);
      o[q].w = f2bf(tp[3 * 65]);
    }
    ushort4* dp = (ushort4*)(dst + (size_t)(n0 + n) * K + k0 + kq);
    *(uint4*)&dp[0] = *(uint4*)&o[0];   // 16B: k q..q+7
    *(uint4*)&dp[2] = *(uint4*)&o[2];   // 16B: k q+8..q+15
  }
}

// ---------- 64x64-tile GEMM + bias (f32 out) for W2 (more blocks, small K) ----------
__global__ __launch_bounds__(256) void gemm_bias64(const unsigned short* __restrict__ A,
                                                   const unsigned short* __restrict__ Bt,
                                                   const float* __restrict__ bias,
                                                   float* __restrict__ C, int N, int K) {
  __shared__ unsigned short As[64 * 32];
  __shared__ unsigned short Bs[64 * 32];
  const int t = threadIdx.x;
  const int lane = t & 63, wid = t >> 6;
  const int wm = (wid & 1) * 32, wn = (wid >> 1) * 32;
  const int m0 = blockIdx.y * 64, n0 = blockIdx.x * 64;
  const int l15 = lane & 15, quad = lane >> 4;
  const int srow = t >> 2, scol = (t & 3) * 8;

  const unsigned short* Ag = A + (size_t)(m0 + srow) * K + scol;
  const unsigned short* Bg = Bt + (size_t)(n0 + srow) * K + scol;
  char* AsB = (char*)As;
  char* BsB = (char*)Bs;
  f32x4 acc[2][2] = {};

  for (int k0 = 0; k0 < K; k0 += 32) {
    gl_lds16(Ag + k0, AsB + t * 16);
    gl_lds16(Bg + k0, BsB + t * 16);
    __syncthreads();
    short8 af[2], bf[2];
#pragma unroll
    for (int mi = 0; mi < 2; mi++)
      af[mi] = *(const short8*)(As + (wm + mi * 16 + l15) * 32 + quad * 8);
#pragma unroll
    for (int ni = 0; ni < 2; ni++)
      bf[ni] = *(const short8*)(Bs + (wn + ni * 16 + l15) * 32 + quad * 8);
#pragma unroll
    for (int mi = 0; mi < 2; mi++)
#pragma unroll
      for (int ni = 0; ni < 2; ni++)
        acc[mi][ni] = __builtin_amdgcn_mfma_f32_16x16x32_bf16(af[mi], bf[ni], acc[mi][ni], 0, 0, 0);
    __syncthreads();
  }
#pragma unroll
  for (int mi = 0; mi < 2; mi++) {
    const int row = m0 + wm + mi * 16 + quad * 4;
#pragma unroll
    for (int ni = 0; ni < 2; ni++) {
      const int col = n0 + wn + ni * 16 + l15;
      const float bv = bias[col];
#pragma unroll
      for (int r = 0; r < 4; r++)
        C[(size_t)(row + r) * N + col] = acc[mi][ni][r] + bv;
    }
  }
}

// ---------- split-K GEMM for W1: K=8192 in 8 chunks of 1024, f32 partials ----------
__global__ __launch_bounds__(256, 4) void gemm_splitk(const unsigned short* __restrict__ A,
                                                      const unsigned short* __restrict__ Bt,
                                                      float* __restrict__ P) {
  __shared__ unsigned short As[128 * 32];
  __shared__ unsigned short Bs[128 * 32];
  const int t = threadIdx.x;
  const int lane = t & 63, wid = t >> 6;
  const int wm = (wid & 1) * 64, wn = (wid >> 1) * 64;
  const int m0 = blockIdx.y * 128, n0 = blockIdx.x * 128;
  const int kbase = blockIdx.z * 1024;
  const int l15 = lane & 15, quad = lane >> 4;
  const int srow = t >> 2, scol = (t & 3) * 8;

  const unsigned short* Ag = A + (size_t)(m0 + srow) * 8192 + kbase + scol;
  const unsigned short* Bg = Bt + (size_t)(n0 + srow) * 8192 + kbase + scol;
  char* AsB = (char*)As;
  char* BsB = (char*)Bs;
  f32x4 acc[4][4] = {};

  for (int k0 = 0; k0 < 1024; k0 += 32) {
    gl_lds16(Ag + k0, AsB + t * 16);
    gl_lds16(Ag + (size_t)64 * 8192 + k0, AsB + 4096 + t * 16);
    gl_lds16(Bg + k0, BsB + t * 16);
    gl_lds16(Bg + (size_t)64 * 8192 + k0, BsB + 4096 + t * 16);
    __syncthreads();
    short8 af[4], bf[4];
#pragma unroll
    for (int mi = 0; mi < 4; mi++)
      af[mi] = *(const short8*)(As + (wm + mi * 16 + l15) * 32 + quad * 8);
#pragma unroll
    for (int ni = 0; ni < 4; ni++)
      bf[ni] = *(const short8*)(Bs + (wn + ni * 16 + l15) * 32 + quad * 8);
#pragma unroll
    for (int mi = 0; mi < 4; mi++)
#pragma unroll
      for (int ni = 0; ni < 4; ni++)
        acc[mi][ni] = __builtin_amdgcn_mfma_f32_16x16x32_bf16(af[mi], bf[ni], acc[mi][ni], 0, 0, 0);
    __syncthreads();
  }
  float* Pb = P + (size_t)blockIdx.z * 2048 * 1024;
#pragma unroll
  for (int mi = 0; mi < 4; mi++) {
    const int row = m0 + wm + mi * 16 + quad * 4;
#pragma unroll
    for (int ni = 0; ni < 4; ni++) {
      const int col = n0 + wn + ni * 16 + l15;
#pragma unroll
      for (int r = 0; r < 4; r++)
        Pb[(size_t)(row + r) * 1024 + col] = acc[mi][ni][r];
    }
  }
}

// ---------- reduce 8 split-K partials + bias, rmsnorm, silu -> xc[:,0:1024] ----------
__global__ __launch_bounds__(256) void reduce_norm_silu(const float* __restrict__ P,
                                                        const float* __restrict__ b1,
                                                        const float* __restrict__ g1,
                                                        unsigned short* __restrict__ xc) {
  const int r = blockIdx.x, t = threadIdx.x;
  const float4* base = (const float4*)(P + (size_t)r * 1024) + t;
  float4 v = *base;
#pragma unroll
  for (int s = 1; s < 8; s++) {
    const float4 p = base[(size_t)s * 2048 * 256];
    v.x += p.x; v.y += p.y; v.z += p.z; v.w += p.w;
  }
  const float4 b4 = *((const float4*)b1 + t);
  v.x += b4.x; v.y += b4.y; v.z += b4.z; v.w += b4.w;
  float ss = v.x * v.x + v.y * v.y + v.z * v.z + v.w * v.w;
  ss = wave_sum(ss);
  __shared__ float red[4];
  if ((t & 63) == 0) red[t >> 6] = ss;
  __syncthreads();
  const float inv = rsqrtf((red[0] + red[1] + red[2] + red[3]) * (1.f / 1024.f) + 1e-6f);
  const float4 g4 = *((const float4*)g1 + t);
  float a0 = v.x * inv * g4.x, a1 = v.y * inv * g4.y, a2 = v.z * inv * g4.z, a3 = v.w * inv * g4.w;
  ushort4 o;
  o.x = f2bf(a0 * sigmoid_f(a0));
  o.y = f2bf(a1 * sigmoid_f(a1));
  o.z = f2bf(a2 * sigmoid_f(a2));
  o.w = f2bf(a3 * sigmoid_f(a3));
  *(ushort4*)(xc + (size_t)r * 3072 + t * 4) = o;
}

// ---------- dyn block GEMM: A = [xc | deter_block_g], B = Wdynt[g], out hidden bf16 ----------
__global__ __launch_bounds__(256, 4) void gemm_dyn(const unsigned short* __restrict__ xc,
                                                   const unsigned short* __restrict__ dbf,
                                                   const unsigned short* __restrict__ Wdt,
                                                   unsigned short* __restrict__ hid) {
  __shared__ unsigned short As[128 * 32];
  __shared__ unsigned short Bs[128 * 32];
  const int t = threadIdx.x;
  const int lane = t & 63, wid = t >> 6;
  const int wm = (wid & 1) * 64, wn = (wid >> 1) * 64;
  const int g = blockIdx.z;
  const int m0 = blockIdx.y * 128, n0 = blockIdx.x * 128;
  const int l15 = lane & 15, quad = lane >> 4;
  const int srow = t >> 2, scol = (t & 3) * 8;

  const unsigned short* Ag1 = xc + (size_t)(m0 + srow) * 3072 + scol;
  const unsigned short* Ag2 = dbf + (size_t)(m0 + srow) * 8192 + g * 1024 + scol - 3072;
  const unsigned short* Bg = Wdt + (size_t)g * 1024 * 4096 + (size_t)(n0 + srow) * 4096 + scol;
  char* AsB = (char*)As;
  char* BsB = (char*)Bs;
  const unsigned short* pa0 = As + (wm + l15) * 32 + quad * 8;
  const unsigned short* pb0 = Bs + (wn + l15) * 32 + quad * 8;
  f32x4 acc[4][4] = {};

  for (int k0 = 0; k0 < 4096; k0 += 32) {
    if (k0 < 3072) {
      gl_lds16(Ag1 + k0, AsB + t * 16);
      gl_lds16(Ag1 + 64 * 3072 + k0, AsB + 4096 + t * 16);
    } else {
      gl_lds16(Ag2 + k0, AsB + t * 16);
      gl_lds16(Ag2 + 64 * 8192 + k0, AsB + 4096 + t * 16);
    }
    gl_lds16(Bg + k0, BsB + t * 16);
    gl_lds16(Bg + 64 * 4096 + k0, BsB + 4096 + t * 16);
    __syncthreads();
    short8 af[4], bf[4];
#pragma unroll
    for (int mi = 0; mi < 4; mi++)
      af[mi] = *(const short8*)(pa0 + mi * 16 * 32);
#pragma unroll
    for (int ni = 0; ni < 4; ni++)
      bf[ni] = *(const short8*)(pb0 + ni * 16 * 32);
#pragma unroll
    for (int mi = 0; mi < 4; mi++)
#pragma unroll
      for (int ni = 0; ni < 4; ni++)
        acc[mi][ni] = __builtin_amdgcn_mfma_f32_16x16x32_bf16(af[mi], bf[ni], acc[mi][ni], 0, 0, 0);
    __syncthreads();
  }
#pragma unroll
  for (int mi = 0; mi < 4; mi++) {
    const int row = m0 + wm + mi * 16 + quad * 4;
#pragma unroll
    for (int ni = 0; ni < 4; ni++) {
      const int col = g * 1024 + n0 + wn + ni * 16 + l15;
#pragma unroll
      for (int r = 0; r < 4; r++)
        hid[(size_t)(row + r) * 8192 + col] = f2bf(acc[mi][ni][r]);
    }
  }
}

// ---------- out block GEMM with fused gates (3 accumulator sets) ----------
__global__ __launch_bounds__(256, 3) void gemm_out3(const unsigned short* __restrict__ hn,
                                                    const unsigned short* __restrict__ Wot,
                                                    const float* __restrict__ deter,
                                                    float* __restrict__ out) {
  __shared__ unsigned short As[128 * 32];       // 8 KB
  __shared__ unsigned short Bs[3 * 64 * 32];    // 12 KB
  const int t = threadIdx.x;
  const int lane = t & 63, wid = t >> 6;
  const int wm = (wid & 1) * 64, wn = (wid >> 1) * 32;
  const int g = blockIdx.z;
  const int m0 = blockIdx.y * 128, n0 = blockIdx.x * 64;
  const int l15 = lane & 15, quad = lane >> 4;
  const int srow = t >> 2, scol = (t & 3) * 8;

  const unsigned short* Ag = hn + (size_t)(m0 + srow) * 8192 + g * 1024 + scol;
  const unsigned short* Bg = Wot + (size_t)g * 3072 * 1024 + (size_t)(n0 + srow) * 1024 + scol;
  char* AsB = (char*)As;
  char* BsB = (char*)Bs;
  f32x4 aR[4][2] = {}, aM[4][2] = {}, aU[4][2] = {};

  for (int k0 = 0; k0 < 1024; k0 += 32) {
    gl_lds16(Ag + k0, AsB + t * 16);
    gl_lds16(Ag + 64 * 8192 + k0, AsB + 4096 + t * 16);
    gl_lds16(Bg + k0, BsB + t * 16);
    gl_lds16(Bg + 1024 * 1024 + k0, BsB + 4096 + t * 16);
    gl_lds16(Bg + 2 * 1024 * 1024 + k0, BsB + 8192 + t * 16);
    __syncthreads();
    short8 af[4], bR[2], bM[2], bU[2];
#pragma unroll
    for (int mi = 0; mi < 4; mi++)
      af[mi] = *(const short8*)(As + (wm + mi * 16 + l15) * 32 + quad * 8);
#pragma unroll
    for (int ni = 0; ni < 2; ni++) {
      bR[ni] = *(const short8*)(Bs + (wn + ni * 16 + l15) * 32 + quad * 8);
      bM[ni] = *(const short8*)(Bs + (64 + wn + ni * 16 + l15) * 32 + quad * 8);
      bU[ni] = *(const short8*)(Bs + (128 + wn + ni * 16 + l15) * 32 + quad * 8);
    }
#pragma unroll
    for (int mi = 0; mi < 4; mi++)
#pragma unroll
      for (int ni = 0; ni < 2; ni++) {
        aR[mi][ni] = __builtin_amdgcn_mfma_f32_16x16x32_bf16(af[mi], bR[ni], aR[mi][ni], 0, 0, 0);
        aM[mi][ni] = __builtin_amdgcn_mfma_f32_16x16x32_bf16(af[mi], bM[ni], aM[mi][ni], 0, 0, 0);
        aU[mi][ni] = __builtin_amdgcn_mfma_f32_16x16x32_bf16(af[mi], bU[ni], aU[mi][ni], 0, 0, 0);
      }
    __syncthreads();
  }
#pragma unroll
  for (int mi = 0; mi < 4; mi++) {
    const int row = m0 + wm + mi * 16 + quad * 4;
#pragma unroll
    for (int ni = 0; ni < 2; ni++) {
      const int col = g * 1024 + n0 + wn + ni * 16 + l15;
#pragma unroll
      for (int r = 0; r < 4; r++) {
        const size_t idx = (size_t)(row + r) * 8192 + col;
        const float rs = sigmoid_f(aR[mi][ni][r]);
        const float cd = tanh_f(rs * aM[mi][ni][r]);
        const float up = sigmoid_f(aU[mi][ni][r] - 1.f);
        out[idx] = up * cd + (1.f - up) * deter[idx];
      }
    }
  }
}

// ---------- rmsnorm + silu over 1024 cols -> xc segment (W2 path) ----------
__global__ __launch_bounds__(256) void norm_silu(const float* __restrict__ tin,
                                                 const float* __restrict__ gw,
                                                 unsigned short* __restrict__ xc, int xcoff) {
  const int r = blockIdx.x, t = threadIdx.x;
  const float4 v = *(const float4*)(tin + (size_t)r * 1024 + t * 4);
  float ss = v.x * v.x + v.y * v.y + v.z * v.z + v.w * v.w;
  ss = wave_sum(ss);
  __shared__ float red[4];
  if ((t & 63) == 0) red[t >> 6] = ss;
  __syncthreads();
  const float inv = rsqrtf((red[0] + red[1] + red[2] + red[3]) * (1.f / 1024.f) + 1e-6f);
  const float4 g4 = *(const float4*)(gw + t * 4);
  float a0 = v.x * inv * g4.x, a1 = v.y * inv * g4.y, a2 = v.z * inv * g4.z, a3 = v.w * inv * g4.w;
  ushort4 o;
  o.x = f2bf(a0 * sigmoid_f(a0));
  o.y = f2bf(a1 * sigmoid_f(a1));
  o.z = f2bf(a2 * sigmoid_f(a2));
  o.w = f2bf(a3 * sigmoid_f(a3));
  *(ushort4*)(xc + (size_t)r * 3072 + xcoff + t * 4) = o;
}

// ---------- action path: normalize, tiny GEMM (K=32), rmsnorm, silu ----------
__global__ __launch_bounds__(256) void act_mlp(const float* __restrict__ action,
                                               const float* __restrict__ W3,
                                               const float* __restrict__ b3,
                                               const float* __restrict__ g3,
                                               unsigned short* __restrict__ xc) {
  const int r = blockIdx.x, t = threadIdx.x;
  __shared__ float sA[32];
  if (t < 32) {
    float a = action[r * 32 + t];
    sA[t] = a / fmaxf(1.f, fabsf(a));
  }
  __syncthreads();
  float acc0 = 0.f, acc1 = 0.f, acc2 = 0.f, acc3 = 0.f;
#pragma unroll 8
  for (int k = 0; k < 32; k++) {
    const float a = sA[k];
    const float* wr = W3 + k * 1024 + t;
    acc0 += a * wr[0];
    acc1 += a * wr[256];
    acc2 += a * wr[512];
    acc3 += a * wr[768];
  }
  acc0 += b3[t]; acc1 += b3[t + 256]; acc2 += b3[t + 512]; acc3 += b3[t + 768];
  float ss = acc0 * acc0 + acc1 * acc1 + acc2 * acc2 + acc3 * acc3;
  ss = wave_sum(ss);
  __shared__ float red[4];
  if ((t & 63) == 0) red[t >> 6] = ss;
  __syncthreads();
  const float inv = rsqrtf((red[0] + red[1] + red[2] + red[3]) * (1.f / 1024.f) + 1e-6f);
  unsigned short* dst = xc + (size_t)r * 3072 + 2048;
  float a0 = acc0 * inv * g3[t], a1 = acc1 * inv * g3[t + 256];
  float a2 = acc2 * inv * g3[t + 512], a3 = acc3 * inv * g3[t + 768];
  dst[t] = f2bf(a0 * sigmoid_f(a0));
  dst[t + 256] = f2bf(a1 * sigmoid_f(a1));
  dst[t + 512] = f2bf(a2 * sigmoid_f(a2));
  dst[t + 768] = f2bf(a3 * sigmoid_f(a3));
}

// ---------- row rmsnorm over 8192 (hidden -> hnorm, bf16) ----------
__global__ __launch_bounds__(256) void hnorm_k(const unsigned short* __restrict__ hid,
                                               const float* __restrict__ gdyn,
                                               unsigned short* __restrict__ hn) {
  const int r = blockIdx.x, t = threadIdx.x;
  const uint4* rp = (const uint4*)(hid + (size_t)r * 8192);
  uint4 v[4];
  float ss = 0.f;
#pragma unroll
  for (int p = 0; p < 4; p++) {
    v[p] = rp[p * 256 + t];
    const unsigned a = v[p].x, b = v[p].y, c = v[p].z, d = v[p].w;
    float x0 = bf2f(a & 0xffff), x1 = bf2f(a >> 16);
    float x2 = bf2f(b & 0xffff), x3 = bf2f(b >> 16);
    float x4 = bf2f(c & 0xffff), x5 = bf2f(c >> 16);
    float x6 = bf2f(d & 0xffff), x7 = bf2f(d >> 16);
    ss += x0 * x0 + x1 * x1 + x2 * x2 + x3 * x3 + x4 * x4 + x5 * x5 + x6 * x6 + x7 * x7;
  }
  ss = wave_sum(ss);
  __shared__ float red[4];
  if ((t & 63) == 0) red[t >> 6] = ss;
  __syncthreads();
  const float inv = rsqrtf((red[0] + red[1] + red[2] + red[3]) * (1.f / 8192.f) + 1e-6f);
  uint4* op = (uint4*)(hn + (size_t)r * 8192);
#pragma unroll
  for (int p = 0; p < 4; p++) {
    const int c0 = (p * 256 + t) * 8;
    const float4 ga = *(const float4*)(gdyn + c0);
    const float4 gb = *(const float4*)(gdyn + c0 + 4);
    const unsigned a = v[p].x, b = v[p].y, c = v[p].z, d = v[p].w;
    unsigned o0 = f2bf(bf2f(a & 0xffff) * inv * ga.x);
    unsigned o1 = f2bf(bf2f(a >> 16) * inv * ga.y);
    unsigned o2 = f2bf(bf2f(b & 0xffff) * inv * ga.z);
    unsigned o3 = f2bf(bf2f(b >> 16) * inv * ga.w);
    unsigned o4 = f2bf(bf2f(c & 0xffff) * inv * gb.x);
    unsigned o5 = f2bf(bf2f(c >> 16) * inv * gb.y);
    unsigned o6 = f2bf(bf2f(d & 0xffff) * inv * gb.z);
    unsigned o7 = f2bf(bf2f(d >> 16) * inv * gb.w);
    uint4 w;
    w.x = o0 | (o1 << 16);
    w.y = o2 | (o3 << 16);
    w.z = o4 | (o5 << 16);
    w.w = o6 | (o7 << 16);
    op[p * 256 + t] = w;
  }
}

extern "C" void kernel_launch(void* const* d_in, const int* in_sizes, int n_in,
                              void* d_out, int out_size, void* d_ws, size_t ws_size,
                              hipStream_t stream) {
  (void)in_sizes; (void)n_in; (void)out_size; (void)ws_size;
  const float* deter  = (const float*)d_in[0];
  const float* stoch  = (const float*)d_in[1];
  const float* action = (const float*)d_in[2];
  const float* W1 = (const float*)d_in[3];
  const float* b1 = (const float*)d_in[4];
  const float* W2 = (const float*)d_in[5];
  const float* b2 = (const float*)d_in[6];
  const float* W3 = (const float*)d_in[7];
  const float* b3 = (const float*)d_in[8];
  const float* g1 = (const float*)d_in[9];
  const float* g2 = (const float*)d_in[10];
  const float* g3 = (const float*)d_in[11];
  const float* Wdyn = (const float*)d_in[12];
  const float* gdyn = (const float*)d_in[13];
  const float* Wout = (const float*)d_in[14];
  float* out = (float*)d_out;
  char* ws = (char*)d_ws;

  unsigned short* W1t = (unsigned short*)(ws + OFF_W1T);
  unsigned short* W2t = (unsigned short*)(ws + OFF_W2T);
  unsigned short* Wdt = (unsigned short*)(ws + OFF_WDT);
  unsigned short* Wot = (unsigned short*)(ws + OFF_WOT);
  unsigned short* dbf = (unsigned short*)(ws + OFF_DBF);
  unsigned short* sbf = (unsigned short*)(ws + OFF_SBF);
  float* t2 = (float*)(ws + OFF_T2);
  unsigned short* xc = (unsigned short*)(ws + OFF_XC);
  unsigned short* hid = (unsigned short*)(ws + OFF_HID);
  unsigned short* hn = (unsigned short*)(ws + OFF_HN);
  float* Pk = (float*)(ws + OFF_HID);  // split-K partials, reused before hid is live

  const dim3 blk(256);

  // 1. casts (64x64 transpose tiles, 16B/lane vectorized writes)
  cast_v<<<dim3(16384), blk, 0, stream>>>((const float4*)deter, (ushort4*)dbf, 2048 * 8192 / 4);
  cast_v<<<dim3(2048), blk, 0, stream>>>((const float4*)stoch, (ushort4*)sbf, 2048 * 1024 / 4);
  cast_transpose<<<dim3(16, 128, 1), blk, 0, stream>>>(W1, W1t, 8192, 1024);
  cast_transpose<<<dim3(16, 16, 1), blk, 0, stream>>>(W2, W2t, 1024, 1024);
  cast_transpose<<<dim3(16, 64, 8), blk, 0, stream>>>(Wdyn, Wdt, 4096, 1024);
  cast_transpose<<<dim3(48, 16, 8), blk, 0, stream>>>(Wout, Wot, 1024, 3072);

  // 2. input projections: W1 via split-K(8) + fused reduce/norm/silu; W2 direct
  gemm_splitk<<<dim3(8, 16, 8), blk, 0, stream>>>(dbf, W1t, Pk);
  gemm_bias64<<<dim3(16, 32), blk, 0, stream>>>(sbf, W2t, b2, t2, 1024, 1024);
  reduce_norm_silu<<<dim3(2048), blk, 0, stream>>>(Pk, b1, g1, xc);
  norm_silu<<<dim3(2048), blk, 0, stream>>>(t2, g2, xc, 1024);
  act_mlp<<<dim3(2048), blk, 0, stream>>>(action, W3, b3, g3, xc);

  // 3. dyn block-diagonal GEMM -> hidden (bf16); overwrites Pk region (xc already built)
  gemm_dyn<<<dim3(8, 16, 8), blk, 0, stream>>>(xc, dbf, Wdt, hid);

  // 4. full-row rmsnorm -> hnorm (bf16)
  hnorm_k<<<dim3(2048), blk, 0, stream>>>(hid, gdyn, hn);

  // 5. out block GEMM + fused gates -> next_deter (f32)
  gemm_out3<<<dim3(16, 16, 8), blk, 0, stream>>>(hn, Wot, deter, out);
}